// Round 2
// baseline (496.065 us; speedup 1.0000x reference)
//
#include <hip/hip_runtime.h>
#include <math.h>

// CTC forward loss, linear-domain alpha recursion with power-of-2 renorm.
// B=256 -> one wave (64 lanes) per batch, one block per batch, 1 block/CU.
// Lane l owns states 4l..4l+3 (+ state 256 as slot 4, meaningful on lane 63).
// Even states are blanks (allow=false) => only prev-lane slot3 is needed
// cross-lane (single shfl_up per step).
//
// Numerics: (+,*) semiring with TWO exact power-of-2 devices:
//  (1) probs pre-scaled by 2^7 so per-step drift ~2^0 (accounted at the end),
//  (2) wave-max renorm every 8 steps re-centering the max at 2^32, giving
//      ~158 bits of representable spread below the concurrent max.
// The 6-stage shfl_xor max-reduce is pipelined one stage per step.

#define T_DIM 1024
#define C_DIM 128
#define U_DIM 128
#define EPSF  1e-7f
#define LN2F  0.6931471805599453f
#define PSCALE 128.0f          // 2^7 per-step pre-scale (exact)
#define PSCALE_LOG2 7
#define TARGET_BEXP 286        // biased exp of scale to recenter max at 2^32: 286-eb

__global__ __launch_bounds__(64) void ctc_alpha_kernel(
    const int*   __restrict__ y_true,   // (B, U) int32
    const float* __restrict__ y_pred,   // (B, T, C) f32 softmax probs
    float*       __restrict__ out,      // (B, 1) f32
    int B)
{
  const int b = blockIdx.x;
  if (b >= B) return;
  const int lane = threadIdx.x;           // 0..63
  const float* __restrict__ p  = y_pred + (size_t)b * (T_DIM * C_DIM);
  const int*   __restrict__ yb = y_true + b * U_DIM;
  const int blank = C_DIM - 1;

  // Labels for this lane's odd states: s=4l+1 -> u=2l ; s=4l+3 -> u=2l+1
  const int ylab0 = yb[2 * lane];
  const int ylab1 = yb[2 * lane + 1];
  int yprev = blank;
  if (lane > 0) yprev = yb[2 * lane - 1];
  const float allow1 = (lane > 0 && ylab0 != blank && ylab0 != yprev) ? 1.0f : 0.0f;
  const float allow3 = (ylab1 != blank && ylab1 != ylab0)             ? 1.0f : 0.0f;
  const float m0     = (lane == 0) ? 0.0f : 1.0f;   // kills alpha[-1] into state 0

  // Row layout across lanes: lane l holds classes (2l, 2l+1) as float2.
  // Gather class c: bpermute from lane c>>1, component c&1.
  const int idx0 = (ylab0 >> 1) << 2, sel0 = ylab0 & 1;
  const int idx1 = (ylab1 >> 1) << 2, sel1 = ylab1 & 1;

  // 16-row register prefetch queue (hides ~900cy HBM latency at ~50cy/step).
  float2 q[16];
#pragma unroll
  for (int i = 0; i < 16; ++i)
    q[i] = ((const float2*)(p + (size_t)i * C_DIM))[lane];

  // Pre-gather row 0 (pipelined gathers: row t+1 gathered during step t).
  float qb_c, q1_c, q3_c;
  {
    float2 r0 = q[0];
    int gx0 = __builtin_amdgcn_ds_bpermute(idx0, __float_as_int(r0.x));
    int gy0 = __builtin_amdgcn_ds_bpermute(idx0, __float_as_int(r0.y));
    int gx1 = __builtin_amdgcn_ds_bpermute(idx1, __float_as_int(r0.x));
    int gy1 = __builtin_amdgcn_ds_bpermute(idx1, __float_as_int(r0.y));
    qb_c = (__int_as_float(__builtin_amdgcn_readlane(__float_as_int(r0.y), 63)) + EPSF) * PSCALE;
    q1_c = (__int_as_float(sel0 ? gy0 : gx0) + EPSF) * PSCALE;
    q3_c = (__int_as_float(sel1 ? gy1 : gx1) + EPSF) * PSCALE;
  }

  // Virtual init: alpha_{-1} = 1 makes t=0 a uniform step:
  // n0 = 1*q_blank on lane0, n1 = 1*q_y0 on lane0, rest 0  == reference alpha0.
  float a0 = (lane == 0) ? 1.0f : 0.0f;
  float a1 = 0.f, a2 = 0.f, a3 = 0.f, a4 = 0.f;
  float red = 0.f;     // pipelined renorm reduction carrier
  int   e_acc = 0;     // accumulated base-2 exponent removed by renorms

  for (int tb = 0; tb < T_DIM; tb += 16) {
#pragma unroll
    for (int u = 0; u < 16; ++u) {
      const int t = tb + u;

      // Prefetch row t+16 into q[u] (its old contents, row t, were consumed
      // by last iteration's gathers). Clamp keeps the tail fault-free.
      int tn = t + 16; if (tn > T_DIM - 1) tn = T_DIM - 1;
      q[u] = ((const float2*)(p + (size_t)tn * C_DIM))[lane];

      // Issue next-row (t+1) gathers now; latency overlaps the alpha update.
      float2 nr = q[(u + 1) & 15];
      int gx0 = __builtin_amdgcn_ds_bpermute(idx0, __float_as_int(nr.x));
      int gy0 = __builtin_amdgcn_ds_bpermute(idx0, __float_as_int(nr.y));
      int gx1 = __builtin_amdgcn_ds_bpermute(idx1, __float_as_int(nr.x));
      int gy1 = __builtin_amdgcn_ds_bpermute(idx1, __float_as_int(nr.y));
      int qbn = __builtin_amdgcn_readlane(__float_as_int(nr.y), 63);

      // Alpha update (states 4l..4l+3, plus state 256 on lane 63).
      float sh3 = __shfl_up(a3, 1);                 // alpha[4l-1] from lane l-1
      float n0 = fmaf(sh3, m0,     a0)      * qb_c; // even: no allow term
      float n1 = fmaf(sh3, allow1, a0 + a1) * q1_c;
      float n2 = (a1 + a2)                  * qb_c;
      float n3 = fmaf(a1,  allow3, a2 + a3) * q3_c;
      float n4 = (a3 + a4)                  * qb_c; // state 256 (lane63); junk elsewhere, harmless
      a0 = n0; a1 = n1; a2 = n2; a3 = n3; a4 = n4;

      // Renorm pipeline, period 8: snapshot -> 6 xor-max stages -> apply.
      const int ph = u & 7;
      if (ph == 0) {
        red = fmaxf(fmaxf(fmaxf(a0, a1), fmaxf(a2, a3)), a4);
      } else if (ph <= 6) {
        red = fmaxf(red, __shfl_xor(red, 1 << (ph - 1)));
      } else {  // ph == 7: red is the wave-wide max snapshot (uniform)
        int eb = (int)((__float_as_uint(red) >> 23) & 0xffu);   // biased exponent
        int sb = TARGET_BEXP - eb;                              // recenter max at 2^32
        if (sb > 254) sb = 254;                                 // clamp to max finite scale
        float sc = __uint_as_float((unsigned)sb << 23);         // exact power of 2
        a0 *= sc; a1 *= sc; a2 *= sc; a3 *= sc; a4 *= sc;
        e_acc += 127 - sb;                                      // stored *= 2^(sb-127)
      }

      // Commit next row's gathered probabilities (pre-scaled by 2^7).
      qb_c = (__int_as_float(qbn) + EPSF) * PSCALE;
      q1_c = (__int_as_float(sel0 ? gy0 : gx0) + EPSF) * PSCALE;
      q3_c = (__int_as_float(sel1 ? gy1 : gx1) + EPSF) * PSCALE;
    }
  }

  if (lane == 63) {
    float s = a3 + a4;                 // alpha[255] + alpha[256]
    s = fmaxf(s, 1e-37f);              // guard log(0) on pathological inputs
    // true log = log(stored) + e_acc*ln2 - (T * 7) * ln2   (undo per-step 2^7)
    float ll = logf(s) + (float)(e_acc - T_DIM * PSCALE_LOG2) * LN2F;
    out[b] = -ll;
  }
}

extern "C" void kernel_launch(void* const* d_in, const int* in_sizes, int n_in,
                              void* d_out, int out_size, void* d_ws, size_t ws_size,
                              hipStream_t stream) {
  const int*   y_true = (const int*)d_in[0];
  const float* y_pred = (const float*)d_in[1];
  float*       out    = (float*)d_out;
  const int B = in_sizes[0] / U_DIM;   // 256
  ctc_alpha_kernel<<<dim3(B), dim3(64), 0, stream>>>(y_true, y_pred, out, B);
}

// Round 3
// 250.005 us; speedup vs baseline: 1.9842x; 1.9842x over previous
//
#include <hip/hip_runtime.h>
#include <math.h>

// CTC forward loss, linear-domain alpha recursion with power-of-2 renorm.
// B=256 -> one wave per batch, one block per CU. Lane l owns states 4l..4l+3
// (+ state 256 as slot 4 on lane 63).
//
// Round-3 changes vs round-2 (all bit-identical numerics):
//  - shfl_up  -> DPP wave_shr:1 (VALU, off the DS pipe)   [~120cy off chain]
//  - shfl_xor renorm -> DPP row_ror max + readlane + s_max [DS-free renorm]
//  - bpermute gathers pipelined GD=4 steps ahead (was 1), 2/step (was 4)
//  - row prefetch deepened to 32 rows (vmcnt slack ~28 steps)

#define T_DIM 1024
#define C_DIM 128
#define U_DIM 128
#define EPSF  1e-7f
#define LN2F  0.6931471805599453f
#define PSCALE 128.0f          // 2^7 per-step pre-scale (exact)
#define PSCALE_LOG2 7
#define TARGET_BEXP 286        // recenter wave-max at 2^32
#define QD 32                  // row prefetch depth == unroll
#define GD 4                   // bpermute pipeline depth (steps ahead)

__device__ __forceinline__ float dpp_wave_shr1(float x) {
  // wave_shr:1 = 0x138; old=0 + invalid-lane -> lane 0 reads exact 0.0f
  return __int_as_float(__builtin_amdgcn_update_dpp(
      0, __float_as_int(x), 0x138, 0xf, 0xf, false));
}
#define ROR_MAX(red, CTRL)                                                   \
  (red) = fmaxf((red), __int_as_float(__builtin_amdgcn_update_dpp(           \
      __float_as_int(red), __float_as_int(red), (CTRL), 0xf, 0xf, false)))

__global__ __launch_bounds__(64) void ctc_alpha_kernel(
    const int*   __restrict__ y_true,   // (B, U) int32
    const float* __restrict__ y_pred,   // (B, T, C) f32 softmax probs
    float*       __restrict__ out,      // (B, 1) f32
    int B)
{
  const int b = blockIdx.x;
  if (b >= B) return;
  const int lane = threadIdx.x;           // 0..63
  const float* __restrict__ p  = y_pred + (size_t)b * (T_DIM * C_DIM);
  const int*   __restrict__ yb = y_true + b * U_DIM;
  const int blank = C_DIM - 1;

  // Labels for this lane's odd states: s=4l+1 -> u=2l ; s=4l+3 -> u=2l+1
  const int ylab0 = yb[2 * lane];
  const int ylab1 = yb[2 * lane + 1];
  int yprev = blank;
  if (lane > 0) yprev = yb[2 * lane - 1];
  const float allow1 = (lane > 0 && ylab0 != blank && ylab0 != yprev) ? 1.0f : 0.0f;
  const float allow3 = (ylab1 != blank && ylab1 != ylab0)             ? 1.0f : 0.0f;

  // Row layout: lane l holds classes (2l, 2l+1) as float2.
  // Gather class c: bpermute from lane c>>1, component c&1 (selected pre-permute).
  const int  idx0 = (ylab0 >> 1) << 2; const bool sel0 = (ylab0 & 1) != 0;
  const int  idx1 = (ylab1 >> 1) << 2; const bool sel1 = (ylab1 & 1) != 0;

  // 32-row register prefetch queue.
  float2 q[QD];
#pragma unroll
  for (int i = 0; i < QD; ++i)
    q[i] = ((const float2*)(p + (size_t)i * C_DIM))[lane];

  // Gather pipeline prefill: rows 0..GD-1.
  int g1[QD], g3[QD], gb[QD];
#pragma unroll
  for (int i = 0; i < GD; ++i) {
    float2 r = q[i];
    g1[i] = __builtin_amdgcn_ds_bpermute(idx0, __float_as_int(sel0 ? r.y : r.x));
    g3[i] = __builtin_amdgcn_ds_bpermute(idx1, __float_as_int(sel1 ? r.y : r.x));
    gb[i] = __builtin_amdgcn_readlane(__float_as_int(r.y), 63);
  }

  // Virtual init: alpha_{-1}=1 on lane0 makes t=0 a uniform step.
  float a0 = (lane == 0) ? 1.0f : 0.0f;
  float a1 = 0.f, a2 = 0.f, a3 = 0.f, a4 = 0.f;
  float red = 0.f;     // pipelined renorm reduction carrier
  int   rmb = 0;       // wave-max bits (uniform) from phase 5
  int   e_acc = 0;     // accumulated base-2 exponent removed by renorms

  for (int tb = 0; tb < T_DIM; tb += QD) {
#pragma unroll
    for (int u = 0; u < QD; ++u) {
      const int t = tb + u;

      // Commit row t's gathered probabilities (pre-scaled by 2^7).
      const float cb = (__int_as_float(gb[u]) + EPSF) * PSCALE;
      const float c1 = (__int_as_float(g1[u]) + EPSF) * PSCALE;
      const float c3 = (__int_as_float(g3[u]) + EPSF) * PSCALE;

      // Issue gathers for row t+GD (consumed GD steps from now).
      {
        float2 nr = q[(u + GD) & (QD - 1)];
        const int w = (u + GD) & (QD - 1);
        g1[w] = __builtin_amdgcn_ds_bpermute(idx0, __float_as_int(sel0 ? nr.y : nr.x));
        g3[w] = __builtin_amdgcn_ds_bpermute(idx1, __float_as_int(sel1 ? nr.y : nr.x));
        gb[w] = __builtin_amdgcn_readlane(__float_as_int(nr.y), 63);
      }

      // Prefetch row t+QD into q[u] (row t's data already fully consumed).
      {
        int tn = t + QD; if (tn > T_DIM - 1) tn = T_DIM - 1;
        q[u] = ((const float2*)(p + (size_t)tn * C_DIM))[lane];
      }

      // Alpha update. sh3 via DPP wave_shr:1 (lane0 -> exact 0, so no mask).
      float sh3 = dpp_wave_shr1(a3);
      float n0 = (a0 + sh3)                 * cb;
      float n1 = fmaf(sh3, allow1, a0 + a1) * c1;
      float n2 = (a1 + a2)                  * cb;
      float n3 = fmaf(a1,  allow3, a2 + a3) * c3;
      float n4 = (a3 + a4)                  * cb;   // state 256 (lane63); junk elsewhere, harmless
      a0 = n0; a1 = n1; a2 = n2; a3 = n3; a4 = n4;

      // Renorm pipeline, period 8 (DS-free: DPP row_ror + readlane + s_max).
      const int ph = u & 7;
      if (ph == 0) {
        red = fmaxf(fmaxf(fmaxf(a0, a1), fmaxf(a2, a3)), a4);
      } else if (ph == 1) { ROR_MAX(red, 0x128);   // row_ror:8
      } else if (ph == 2) { ROR_MAX(red, 0x124);   // row_ror:4
      } else if (ph == 3) { ROR_MAX(red, 0x122);   // row_ror:2
      } else if (ph == 4) { ROR_MAX(red, 0x121);   // row_ror:1 -> row(16) max in all lanes
      } else if (ph == 5) {
        // Cross-row: 4 readlanes + int max (positive floats order as ints).
        int r0 = __builtin_amdgcn_readlane(__float_as_int(red), 0);
        int r1 = __builtin_amdgcn_readlane(__float_as_int(red), 16);
        int r2 = __builtin_amdgcn_readlane(__float_as_int(red), 32);
        int r3 = __builtin_amdgcn_readlane(__float_as_int(red), 48);
        int m01 = r0 > r1 ? r0 : r1;
        int m23 = r2 > r3 ? r2 : r3;
        rmb = m01 > m23 ? m01 : m23;
      } else if (ph == 7) {
        int eb = (rmb >> 23) & 0xff;                      // biased exponent of wave max
        int sb = TARGET_BEXP - eb;                        // recenter max at 2^32
        if (sb > 254) sb = 254;
        float sc = __uint_as_float((unsigned)sb << 23);   // exact power of 2
        a0 *= sc; a1 *= sc; a2 *= sc; a3 *= sc; a4 *= sc;
        e_acc += 127 - sb;
      }
    }
  }

  if (lane == 63) {
    float s = a3 + a4;                 // alpha[255] + alpha[256]
    s = fmaxf(s, 1e-37f);
    // true log = log(stored) + e_acc*ln2 - (T*7)*ln2  (undo per-step 2^7)
    float ll = logf(s) + (float)(e_acc - T_DIM * PSCALE_LOG2) * LN2F;
    out[b] = -ll;
  }
}

extern "C" void kernel_launch(void* const* d_in, const int* in_sizes, int n_in,
                              void* d_out, int out_size, void* d_ws, size_t ws_size,
                              hipStream_t stream) {
  const int*   y_true = (const int*)d_in[0];
  const float* y_pred = (const float*)d_in[1];
  float*       out    = (float*)d_out;
  const int B = in_sizes[0] / U_DIM;   // 256
  ctc_alpha_kernel<<<dim3(B), dim3(64), 0, stream>>>(y_true, y_pred, out, B);
}